// Round 4
// baseline (659.101 us; speedup 1.0000x reference)
//
#include <hip/hip_runtime.h>
#include <hip/hip_bf16.h>

typedef __attribute__((ext_vector_type(8))) short bf16x8;
typedef __attribute__((ext_vector_type(4))) float f32x4;

#define XT_STRIDE 72   // ints per row: 64 p + 8 pad (16B-aligned rows, conflict-free b128 reads)

// ---------------- Phase 0: pre-split conv_w into frag-ready hi/lo bf16 ----------------
__global__ void p0_wsplit(const float* __restrict__ convw,
                          short* __restrict__ whi, short* __restrict__ wlo)
{
    int e = blockIdx.x * 256 + threadIdx.x;
    if (e >= 2048) return;
    int lane = e & 63;
    int kstep = (e >> 6) & 7;
    int nt = e >> 9;
    int cluster = nt * 16 + (lane & 15);
    int ch0 = kstep * 32 + (lane >> 4) * 8;
    const float* src = convw + cluster * 256 + ch0;
    #pragma unroll
    for (int j = 0; j < 8; ++j) {
        float x = src[j];
        unsigned u = __float_as_uint(x);
        unsigned uh = u & 0xffff0000u;
        float r = x - __uint_as_float(uh);
        whi[e * 8 + j] = (short)(u >> 16);
        wlo[e * 8 + j] = (short)(__float_as_uint(r) >> 16);
    }
}

// ---------------- Phase 2: count, prefix, counting-sort scatter ----------------
__global__ __launch_bounds__(256) void p2_count(const int* __restrict__ bids,
                                                int* __restrict__ cnts, int N)
{
    __shared__ int cnt[8];
    const int t = threadIdx.x;
    if (t < 8) cnt[t] = 0;
    __syncthreads();
    int p = blockIdx.x * 256 + t;
    if (p < N) atomicAdd(&cnt[bids[p]], 1);
    __syncthreads();
    if (t < 8) atomicAdd(&cnts[t], cnt[t]);
}

__global__ void p2_offsets(const int* __restrict__ cnts, int* __restrict__ offs, int* __restrict__ cur)
{
    if (threadIdx.x == 0) {
        int acc = 0;
        for (int b = 0; b < 8; ++b) { offs[b] = acc; cur[b] = acc; acc += cnts[b]; }
        offs[8] = acc;
    }
}

__global__ __launch_bounds__(256) void p2_scatter(
    const int* __restrict__ bids, int* __restrict__ cur, int* __restrict__ perm, int N)
{
    __shared__ int lcnt[8], lbase[8];
    const int t = threadIdx.x;
    if (t < 8) lcnt[t] = 0;
    __syncthreads();
    int p = blockIdx.x * 256 + t;
    int b = 0, my = 0;
    bool ok = p < N;
    if (ok) { b = bids[p]; my = atomicAdd(&lcnt[b], 1); }
    __syncthreads();
    if (t < 8) lbase[t] = atomicAdd(&cur[t], lcnt[t]);
    __syncthreads();
    if (ok) perm[lbase[b] + my] = p;
}

// ---------------- Fused p1+p3: logits+softmax+aggregation, all in one kernel ----------------
// Block = 256 thr = 4 waves, owns (batch b, slice sp). Loops 64-point groups:
//   GEMM1 (x·Wt via split-bf16 MFMA) -> softmax in-register -> LDS transpose (packed hi|lo)
//   GEMM2 (soft'^T·x, soft' = soft*invnorm) accumulating 64k x 256c tile.
// soft/x never round-trip through global memory.
__global__ __launch_bounds__(256, 2) void fused13(
    const float* __restrict__ feat,
    const short* __restrict__ whi, const short* __restrict__ wlo,
    const float* __restrict__ convb,
    const int* __restrict__ perm, const int* __restrict__ offs,
    float* __restrict__ partial, float* __restrict__ S, int split)
{
    __shared__ unsigned xT[128 * XT_STRIDE];  // x packed (hi<<16|lo), rows c within half, cols p  (36.9 KB)
    __shared__ unsigned sT[64 * XT_STRIDE];   // soft*inv packed, rows k, cols p                   (18.4 KB)

    const int b  = blockIdx.x / split;
    const int sp = blockIdx.x % split;
    const int start = offs[b], end = offs[b + 1];
    const int len = end - start;
    const int chunk = (len + split - 1) / split;
    const int s0 = start + sp * chunk;
    int myLen = min(chunk, end - s0);
    if (myLen < 0) myLen = 0;

    const int t = threadIdx.x;
    const int w = t >> 6, lane = t & 63;
    const int m = lane & 15, quad = lane >> 4;

    const bf16x8* WH = (const bf16x8*)whi;
    const bf16x8* WL = (const bf16x8*)wlo;

    float bias[4];
    #pragma unroll
    for (int nt = 0; nt < 4; ++nt) bias[nt] = convb[nt * 16 + m];

    f32x4 acc2[16];
    #pragma unroll
    for (int ct = 0; ct < 16; ++ct) acc2[ct] = (f32x4){0.f, 0.f, 0.f, 0.f};
    float saccv[4] = {0.f, 0.f, 0.f, 0.f};

    const int nIter = (myLen + 63) >> 6;
    for (int it = 0; it < nIter; ++it) {
        // ---------- GEMM1: logits for this 64-point group ----------
        const int pl = it * 64 + w * 16 + m;           // this lane's A-frag point
        const int pid = (pl < myLen) ? perm[s0 + pl] : -1;
        const bool valid = pid >= 0;
        const float* frow = feat + (size_t)pid * 256 + quad * 8;

        f32x4 acc1[4];
        #pragma unroll
        for (int nt = 0; nt < 4; ++nt) acc1[nt] = (f32x4){0.f, 0.f, 0.f, 0.f};
        float ssq = 0.f;
        unsigned xint[64];                              // packed unnormalized x, [ks][j]

        #pragma unroll
        for (int ks = 0; ks < 8; ++ks) {
            float x[8];
            if (valid) {
                float4 v0 = *(const float4*)(frow + ks * 32);
                float4 v1 = *(const float4*)(frow + ks * 32 + 4);
                x[0] = v0.x; x[1] = v0.y; x[2] = v0.z; x[3] = v0.w;
                x[4] = v1.x; x[5] = v1.y; x[6] = v1.z; x[7] = v1.w;
            } else {
                #pragma unroll
                for (int j = 0; j < 8; ++j) x[j] = 0.f;
            }
            bf16x8 ahi, alo;
            #pragma unroll
            for (int j = 0; j < 8; ++j) {
                unsigned u = __float_as_uint(x[j]);
                float r = x[j] - __uint_as_float(u & 0xffff0000u);
                unsigned lo = __float_as_uint(r) >> 16;
                ahi[j] = (short)(u >> 16);
                alo[j] = (short)lo;
                xint[ks * 8 + j] = (u & 0xffff0000u) | lo;
                ssq += x[j] * x[j];
            }
            #pragma unroll
            for (int nt = 0; nt < 4; ++nt) {
                bf16x8 bhi = WH[(nt * 8 + ks) * 64 + lane];
                bf16x8 blo = WL[(nt * 8 + ks) * 64 + lane];
                acc1[nt] = __builtin_amdgcn_mfma_f32_16x16x32_bf16(ahi, bhi, acc1[nt], 0, 0, 0);
                acc1[nt] = __builtin_amdgcn_mfma_f32_16x16x32_bf16(ahi, blo, acc1[nt], 0, 0, 0);
                acc1[nt] = __builtin_amdgcn_mfma_f32_16x16x32_bf16(alo, bhi, acc1[nt], 0, 0, 0);
            }
        }
        // full ||x||^2 for point (w*16+m) lands in every lane of the wave
        ssq += __shfl_xor(ssq, 16);
        ssq += __shfl_xor(ssq, 32);

        // ---------- softmax epilogue (C-layout: cluster=nt*16+m, point row=quad*4+r) ----------
        #pragma unroll
        for (int r = 0; r < 4; ++r) {
            int prow = quad * 4 + r;
            int plp = it * 64 + w * 16 + prow;
            bool pv = plp < myLen;
            float psq = __shfl(ssq, (lane & 48) | prow);   // same quad, lane m=prow
            float inv = rsqrtf(fmaxf(psq, 1e-24f));
            float v[4];
            #pragma unroll
            for (int nt = 0; nt < 4; ++nt) v[nt] = acc1[nt][r] * inv + bias[nt];
            float mx = fmaxf(fmaxf(v[0], v[1]), fmaxf(v[2], v[3]));
            #pragma unroll
            for (int off = 8; off >= 1; off >>= 1) mx = fmaxf(mx, __shfl_xor(mx, off));
            float e[4]; float s = 0.f;
            #pragma unroll
            for (int nt = 0; nt < 4; ++nt) { e[nt] = __expf(v[nt] - mx); s += e[nt]; }
            #pragma unroll
            for (int off = 8; off >= 1; off >>= 1) s += __shfl_xor(s, off);
            float rs = 1.0f / s;
            #pragma unroll
            for (int nt = 0; nt < 4; ++nt) {
                float so = pv ? e[nt] * rs : 0.f;
                saccv[nt] += so;                 // S uses raw soft
                float sos = so * inv;            // fold 1/||x|| into soft for GEMM2
                unsigned u = __float_as_uint(sos);
                float rr = sos - __uint_as_float(u & 0xffff0000u);
                unsigned pk = (u & 0xffff0000u) | (__float_as_uint(rr) >> 16);
                sT[(nt * 16 + m) * XT_STRIDE + w * 16 + prow] = pk;
            }
        }

        // ---------- GEMM2 over two c-halves ----------
        #pragma unroll
        for (int h = 0; h < 2; ++h) {
            // stage x half h (rows c-128h), from registers
            #pragma unroll
            for (int kk = 0; kk < 4; ++kk) {
                #pragma unroll
                for (int j = 0; j < 8; ++j) {
                    int cr = kk * 32 + quad * 8 + j;
                    xT[cr * XT_STRIDE + w * 16 + m] = xint[(h * 4 + kk) * 8 + j];
                }
            }
            __syncthreads();   // sT (h=0) + xT half visible
            // A-frags: wave w owns cluster rows w*16..w*16+15
            bf16x8 ah[2], al[2];
            #pragma unroll
            for (int ks2 = 0; ks2 < 2; ++ks2) {
                const unsigned* ap = &sT[(w * 16 + m) * XT_STRIDE + ks2 * 32 + quad * 8];
                #pragma unroll
                for (int j = 0; j < 8; ++j) {
                    unsigned pk = ap[j];
                    ah[ks2][j] = (short)(pk >> 16);
                    al[ks2][j] = (short)(pk & 0xffffu);
                }
            }
            #pragma unroll
            for (int ctl = 0; ctl < 8; ++ctl) {
                const int ct = h * 8 + ctl;
                #pragma unroll
                for (int ks2 = 0; ks2 < 2; ++ks2) {
                    const unsigned* bp = &xT[(ctl * 16 + m) * XT_STRIDE + ks2 * 32 + quad * 8];
                    bf16x8 bh, bl;
                    #pragma unroll
                    for (int j = 0; j < 8; ++j) {
                        unsigned pk = bp[j];
                        bh[j] = (short)(pk >> 16);
                        bl[j] = (short)(pk & 0xffffu);
                    }
                    acc2[ct] = __builtin_amdgcn_mfma_f32_16x16x32_bf16(ah[ks2], bh, acc2[ct], 0, 0, 0);
                    acc2[ct] = __builtin_amdgcn_mfma_f32_16x16x32_bf16(ah[ks2], bl, acc2[ct], 0, 0, 0);
                    acc2[ct] = __builtin_amdgcn_mfma_f32_16x16x32_bf16(al[ks2], bh, acc2[ct], 0, 0, 0);
                }
            }
            __syncthreads();   // readers done before next stage overwrites
        }
    }

    // ---------- store partial 64x256 tile (no atomics) + S ----------
    float* dst = partial + (size_t)(b * split + sp) * 64 * 256;
    #pragma unroll
    for (int ct = 0; ct < 16; ++ct)
        #pragma unroll
        for (int r = 0; r < 4; ++r)
            dst[(w * 16 + quad * 4 + r) * 256 + ct * 16 + m] = acc2[ct][r];

    #pragma unroll
    for (int nt = 0; nt < 4; ++nt) {
        float sv = saccv[nt];
        sv += __shfl_xor(sv, 16);
        sv += __shfl_xor(sv, 32);
        if (quad == 0) atomicAdd(S + b * 64 + nt * 16 + m, sv);
    }
}

// ---------------- Phase 4a: reduce partials, subtract S*centroid, intra-normalize ----------------
__global__ __launch_bounds__(256) void p4a_vlad(
    const float* __restrict__ partial, const float* __restrict__ S,
    const float* __restrict__ cents, float* __restrict__ v, int split)
{
    const int b = blockIdx.x >> 6, k = blockIdx.x & 63;
    const int t = threadIdx.x;
    float sum = 0.f;
    const float* base = partial + ((size_t)(b * split) * 64 + k) * 256 + t;
    for (int sp = 0; sp < split; ++sp)
        sum += base[(size_t)sp * 64 * 256];
    float val = sum - S[b * 64 + k] * cents[k * 256 + t];
    float sq = val * val;
    #pragma unroll
    for (int off = 32; off >= 1; off >>= 1) sq += __shfl_xor(sq, off);
    __shared__ float wsum[4];
    if ((t & 63) == 0) wsum[t >> 6] = sq;
    __syncthreads();
    float tot = wsum[0] + wsum[1] + wsum[2] + wsum[3];
    float r = 1.0f / fmaxf(sqrtf(tot), 1e-12f);
    v[b * 16384 + k * 256 + t] = val * r;
}

// ---------------- Phase 4b: FC out = v @ fc_w.T + fc_b ----------------
__global__ __launch_bounds__(256) void p4b_fc(
    const float* __restrict__ v, const float* __restrict__ fcw,
    const float* __restrict__ fcb, float* __restrict__ pre)
{
    const int t = threadIdx.x;
    const int o0 = blockIdx.x * 4;
    float acc[4][8] = {};
    for (int it = 0; it < 64; ++it) {
        int i = it * 256 + t;
        float wv[4];
        #pragma unroll
        for (int oo = 0; oo < 4; ++oo) wv[oo] = fcw[(size_t)(o0 + oo) * 16384 + i];
        #pragma unroll
        for (int b = 0; b < 8; ++b) {
            float vv = v[b * 16384 + i];
            #pragma unroll
            for (int oo = 0; oo < 4; ++oo) acc[oo][b] += wv[oo] * vv;
        }
    }
    __shared__ float red[32][4];
    #pragma unroll
    for (int oo = 0; oo < 4; ++oo)
        #pragma unroll
        for (int b = 0; b < 8; ++b) {
            float sv = acc[oo][b];
            #pragma unroll
            for (int off = 32; off >= 1; off >>= 1) sv += __shfl_xor(sv, off);
            if ((t & 63) == 0) red[oo * 8 + b][t >> 6] = sv;
        }
    __syncthreads();
    if (t < 32) {
        int oo = t >> 3, b = t & 7;
        float sv = red[t][0] + red[t][1] + red[t][2] + red[t][3];
        pre[b * 1024 + o0 + oo] = sv + fcb[o0 + oo];
    }
}

// ---------------- Phase 5: final l2norm over 1024 ----------------
__global__ __launch_bounds__(256) void p5_norm(const float* __restrict__ pre, float* __restrict__ out)
{
    const int b = blockIdx.x, t = threadIdx.x;
    float vals[4];
    float sq = 0.f;
    #pragma unroll
    for (int i = 0; i < 4; ++i) {
        vals[i] = pre[b * 1024 + t + 256 * i];
        sq += vals[i] * vals[i];
    }
    #pragma unroll
    for (int off = 32; off >= 1; off >>= 1) sq += __shfl_xor(sq, off);
    __shared__ float wsum[4];
    if ((t & 63) == 0) wsum[t >> 6] = sq;
    __syncthreads();
    float tot = wsum[0] + wsum[1] + wsum[2] + wsum[3];
    float r = 1.0f / fmaxf(sqrtf(tot), 1e-12f);
    #pragma unroll
    for (int i = 0; i < 4; ++i) out[b * 1024 + t + 256 * i] = vals[i] * r;
}

extern "C" void kernel_launch(void* const* d_in, const int* in_sizes, int n_in,
                              void* d_out, int out_size, void* d_ws, size_t ws_size,
                              hipStream_t stream)
{
    const float* feat  = (const float*)d_in[0];
    const int*   bids  = (const int*)d_in[1];
    const float* cents = (const float*)d_in[2];
    const float* convw = (const float*)d_in[3];
    const float* convb = (const float*)d_in[4];
    const float* fcw   = (const float*)d_in[5];
    const float* fcb   = (const float*)d_in[6];
    float* out = (float*)d_out;

    const int N = in_sizes[0] / 256;  // 200000

    // ---- adaptive split: 64 => 512 blocks = exactly 2 resident per CU
    const size_t base_floats = 16384 /*whi+wlo as float-equiv*/ + 512 /*S*/
                             + 8 * 16384 /*v*/ + 8192 /*pre*/;
    const size_t base_ints = (size_t)N + 8 + 9 + 8;
    int split = 64;
    while (split > 16) {
        size_t tot = (base_floats + (size_t)split * 8 * 16384) * 4 + base_ints * 4;
        if (tot <= ws_size) break;
        split -= 16;
    }

    short* whi = (short*)d_ws;                          // 16384 shorts
    short* wlo = whi + 16384;                           // 16384 shorts
    float* partial = (float*)(wlo + 16384);             // split*8*64*256
    float* S    = partial + (size_t)split * 8 * 16384;  // 512
    float* v    = S + 512;                              // 8*16384
    float* pre  = v + 8 * 16384;                        // 8192
    int* perm = (int*)(pre + 8192);                     // N
    int* cnts = perm + N;                               // 8
    int* offs = cnts + 8;                               // 9
    int* cur  = offs + 9;                               // 8

    hipMemsetAsync(S, 0, 512 * sizeof(float), stream);
    hipMemsetAsync(cnts, 0, 8 * sizeof(int), stream);

    p0_wsplit<<<8, 256, 0, stream>>>(convw, whi, wlo);
    p2_count<<<(N + 255) / 256, 256, 0, stream>>>(bids, cnts, N);
    p2_offsets<<<1, 64, 0, stream>>>(cnts, offs, cur);
    p2_scatter<<<(N + 255) / 256, 256, 0, stream>>>(bids, cur, perm, N);
    fused13<<<8 * split, 256, 0, stream>>>(feat, whi, wlo, convb, perm, offs, partial, S, split);
    p4a_vlad<<<512, 256, 0, stream>>>(partial, S, cents, v, split);
    p4b_fc<<<256, 256, 0, stream>>>(v, fcw, fcb, pre);
    p5_norm<<<8, 256, 0, stream>>>(pre, out);
}

// Round 5
// 607.901 us; speedup vs baseline: 1.0842x; 1.0842x over previous
//
#include <hip/hip_runtime.h>
#include <hip/hip_bf16.h>

typedef __attribute__((ext_vector_type(8))) short bf16x8;
typedef __attribute__((ext_vector_type(4))) short short4v;
typedef __attribute__((ext_vector_type(4))) float f32x4;

#define STR 72   // shorts per LDS row: 64 cols + 8 pad -> 144 B rows (16B-aligned, optimal bank spread)

// ---------------- Phase 0: pre-split conv_w into frag-ready hi/lo bf16 ----------------
__global__ void p0_wsplit(const float* __restrict__ convw,
                          short* __restrict__ whi, short* __restrict__ wlo)
{
    int e = blockIdx.x * 256 + threadIdx.x;
    if (e >= 2048) return;
    int lane = e & 63;
    int kstep = (e >> 6) & 7;
    int nt = e >> 9;
    int cluster = nt * 16 + (lane & 15);
    int ch0 = kstep * 32 + (lane >> 4) * 8;
    const float* src = convw + cluster * 256 + ch0;
    #pragma unroll
    for (int j = 0; j < 8; ++j) {
        float x = src[j];
        unsigned u = __float_as_uint(x);
        float r = x - __uint_as_float(u & 0xffff0000u);
        whi[e * 8 + j] = (short)(u >> 16);
        wlo[e * 8 + j] = (short)(__float_as_uint(r) >> 16);
    }
}

// ---------------- Phase 2: count, prefix, counting-sort scatter ----------------
__global__ __launch_bounds__(256) void p2_count(const int* __restrict__ bids,
                                                int* __restrict__ cnts, int N)
{
    __shared__ int cnt[8];
    const int t = threadIdx.x;
    if (t < 8) cnt[t] = 0;
    __syncthreads();
    int p = blockIdx.x * 256 + t;
    if (p < N) atomicAdd(&cnt[bids[p]], 1);
    __syncthreads();
    if (t < 8) atomicAdd(&cnts[t], cnt[t]);
}

__global__ void p2_offsets(const int* __restrict__ cnts, int* __restrict__ offs, int* __restrict__ cur)
{
    if (threadIdx.x == 0) {
        int acc = 0;
        for (int b = 0; b < 8; ++b) { offs[b] = acc; cur[b] = acc; acc += cnts[b]; }
        offs[8] = acc;
    }
}

__global__ __launch_bounds__(256) void p2_scatter(
    const int* __restrict__ bids, int* __restrict__ cur, int* __restrict__ perm, int N)
{
    __shared__ int lcnt[8], lbase[8];
    const int t = threadIdx.x;
    if (t < 8) lcnt[t] = 0;
    __syncthreads();
    int p = blockIdx.x * 256 + t;
    int b = 0, my = 0;
    bool ok = p < N;
    if (ok) { b = bids[p]; my = atomicAdd(&lcnt[b], 1); }
    __syncthreads();
    if (t < 8) lbase[t] = atomicAdd(&cur[t], lcnt[t]);
    __syncthreads();
    if (ok) perm[lbase[b] + my] = p;
}

// ---------------- Fused: logits + softmax + aggregation (v2, spill-free) ----------------
// Block = 256 thr = 4 waves, owns (batch b, slice sp). Per 64-point group:
//   GEMM1 (x.Wt, split-bf16 MFMA, x discarded) -> softmax in-register -> sT(b64 writes)
//   per c-half: re-gather x from global (L2-hot) transposed into LDS (b128 writes,
//   split hi/lo so frags load with zero unpack) -> GEMM2 accumulating 64k x 256c.
__global__ __launch_bounds__(256, 2) void fused13(
    const float* __restrict__ feat,
    const short* __restrict__ whi, const short* __restrict__ wlo,
    const float* __restrict__ convb,
    const int* __restrict__ perm, const int* __restrict__ offs,
    float* __restrict__ partial, float* __restrict__ S, int split)
{
    __shared__ short xh[128 * STR];  // x hi, rows = c_local (within half), cols = p   18.4 KB
    __shared__ short xl[128 * STR];  // x lo                                           18.4 KB
    __shared__ short sh[64 * STR];   // soft*inv hi, rows = cluster, cols = p           9.2 KB
    __shared__ short sl[64 * STR];   //                                                 9.2 KB

    const int b  = blockIdx.x / split;
    const int sp = blockIdx.x % split;
    const int start = offs[b], end = offs[b + 1];
    const int len = end - start;
    const int chunk = (len + split - 1) / split;
    const int s0 = start + sp * chunk;
    int myLen = min(chunk, end - s0);
    if (myLen < 0) myLen = 0;

    const int t = threadIdx.x;
    const int w = t >> 6, lane = t & 63;
    const int m = lane & 15, quad = lane >> 4;

    const bf16x8* WH = (const bf16x8*)whi;
    const bf16x8* WL = (const bf16x8*)wlo;

    float bias[4];
    #pragma unroll
    for (int nt = 0; nt < 4; ++nt) bias[nt] = convb[nt * 16 + m];

    f32x4 acc2[16];
    #pragma unroll
    for (int ct = 0; ct < 16; ++ct) acc2[ct] = (f32x4){0.f, 0.f, 0.f, 0.f};
    float saccv[4] = {0.f, 0.f, 0.f, 0.f};

    const int nIter = (myLen + 63) >> 6;
    for (int it = 0; it < nIter; ++it) {
        // ---------- GEMM1: logits for 64-point group (x discarded after use) ----------
        const int pl = it * 64 + w * 16 + m;
        const int pid = (pl < myLen) ? perm[s0 + pl] : -1;
        const bool valid = pid >= 0;
        const float* frow = feat + (size_t)pid * 256 + quad * 8;

        f32x4 acc1[4];
        #pragma unroll
        for (int nt = 0; nt < 4; ++nt) acc1[nt] = (f32x4){0.f, 0.f, 0.f, 0.f};
        float ssq = 0.f;

        #pragma unroll
        for (int ks = 0; ks < 8; ++ks) {
            float x[8];
            if (valid) {
                float4 v0 = *(const float4*)(frow + ks * 32);
                float4 v1 = *(const float4*)(frow + ks * 32 + 4);
                x[0] = v0.x; x[1] = v0.y; x[2] = v0.z; x[3] = v0.w;
                x[4] = v1.x; x[5] = v1.y; x[6] = v1.z; x[7] = v1.w;
            } else {
                #pragma unroll
                for (int j = 0; j < 8; ++j) x[j] = 0.f;
            }
            bf16x8 ahi, alo;
            #pragma unroll
            for (int j = 0; j < 8; ++j) {
                unsigned u = __float_as_uint(x[j]);
                float r = x[j] - __uint_as_float(u & 0xffff0000u);
                ahi[j] = (short)(u >> 16);
                alo[j] = (short)(__float_as_uint(r) >> 16);
                ssq += x[j] * x[j];
            }
            #pragma unroll
            for (int nt = 0; nt < 4; ++nt) {
                bf16x8 bhi = WH[(nt * 8 + ks) * 64 + lane];
                bf16x8 blo = WL[(nt * 8 + ks) * 64 + lane];
                acc1[nt] = __builtin_amdgcn_mfma_f32_16x16x32_bf16(ahi, bhi, acc1[nt], 0, 0, 0);
                acc1[nt] = __builtin_amdgcn_mfma_f32_16x16x32_bf16(ahi, blo, acc1[nt], 0, 0, 0);
                acc1[nt] = __builtin_amdgcn_mfma_f32_16x16x32_bf16(alo, bhi, acc1[nt], 0, 0, 0);
            }
        }
        ssq += __shfl_xor(ssq, 16);
        ssq += __shfl_xor(ssq, 32);

        // ---------- softmax (C-layout: cluster = nt*16+m, point row = quad*4+r) ----------
        float sov[4][4];   // soft * invnorm, [nt][r]
        #pragma unroll
        for (int r = 0; r < 4; ++r) {
            int prow = quad * 4 + r;
            int plp = it * 64 + w * 16 + prow;
            bool pv = plp < myLen;
            float psq = __shfl(ssq, (lane & 48) | prow);
            float inv = rsqrtf(fmaxf(psq, 1e-24f));
            float v[4];
            #pragma unroll
            for (int nt = 0; nt < 4; ++nt) v[nt] = acc1[nt][r] * inv + bias[nt];
            float mx = fmaxf(fmaxf(v[0], v[1]), fmaxf(v[2], v[3]));
            #pragma unroll
            for (int off = 8; off >= 1; off >>= 1) mx = fmaxf(mx, __shfl_xor(mx, off));
            float e[4]; float s = 0.f;
            #pragma unroll
            for (int nt = 0; nt < 4; ++nt) { e[nt] = __expf(v[nt] - mx); s += e[nt]; }
            #pragma unroll
            for (int off = 8; off >= 1; off >>= 1) s += __shfl_xor(s, off);
            float rs = 1.0f / s;
            #pragma unroll
            for (int nt = 0; nt < 4; ++nt) {
                float so = pv ? e[nt] * rs : 0.f;
                saccv[nt] += so;
                sov[nt][r] = so * inv;
            }
        }
        // write sT as b64 (4 consecutive point-cols per row)
        #pragma unroll
        for (int nt = 0; nt < 4; ++nt) {
            short4v hi4, lo4;
            #pragma unroll
            for (int r = 0; r < 4; ++r) {
                float sos = sov[nt][r];
                unsigned u = __float_as_uint(sos);
                float rr = sos - __uint_as_float(u & 0xffff0000u);
                hi4[r] = (short)(u >> 16);
                lo4[r] = (short)(__float_as_uint(rr) >> 16);
            }
            *(short4v*)&sh[(nt * 16 + m) * STR + w * 16 + quad * 4] = hi4;
            *(short4v*)&sl[(nt * 16 + m) * STR + w * 16 + quad * 4] = lo4;
        }

        // wave-uniform pids for staging (readlane broadcasts)
        int pjv[16];
        #pragma unroll
        for (int j = 0; j < 16; ++j) pjv[j] = __shfl(pid, j);

        // ---------- GEMM2 over two c-halves ----------
        #pragma unroll
        for (int h = 0; h < 2; ++h) {
            // stage x transposed: lane = channel row, wave covers its own 16 point-cols
            #pragma unroll
            for (int cg = 0; cg < 2; ++cg) {
                int cl = cg * 64 + lane;          // c_local 0..127
                int c  = h * 128 + cl;            // global channel
                float v[16];
                #pragma unroll
                for (int j = 0; j < 16; ++j)
                    v[j] = (pjv[j] >= 0) ? feat[(size_t)pjv[j] * 256 + c] : 0.f;
                bf16x8 h0, l0, h1, l1;
                #pragma unroll
                for (int j = 0; j < 8; ++j) {
                    unsigned u = __float_as_uint(v[j]);
                    float r = v[j] - __uint_as_float(u & 0xffff0000u);
                    h0[j] = (short)(u >> 16);
                    l0[j] = (short)(__float_as_uint(r) >> 16);
                    unsigned u2 = __float_as_uint(v[8 + j]);
                    float r2 = v[8 + j] - __uint_as_float(u2 & 0xffff0000u);
                    h1[j] = (short)(u2 >> 16);
                    l1[j] = (short)(__float_as_uint(r2) >> 16);
                }
                *(bf16x8*)&xh[cl * STR + w * 16]     = h0;
                *(bf16x8*)&xh[cl * STR + w * 16 + 8] = h1;
                *(bf16x8*)&xl[cl * STR + w * 16]     = l0;
                *(bf16x8*)&xl[cl * STR + w * 16 + 8] = l1;
            }
            __syncthreads();   // sT (h=0) + xT half visible

            bf16x8 ah[2], al[2];
            #pragma unroll
            for (int ks2 = 0; ks2 < 2; ++ks2) {
                ah[ks2] = *(const bf16x8*)&sh[(w * 16 + m) * STR + ks2 * 32 + quad * 8];
                al[ks2] = *(const bf16x8*)&sl[(w * 16 + m) * STR + ks2 * 32 + quad * 8];
            }
            #pragma unroll
            for (int ctl = 0; ctl < 8; ++ctl) {
                const int ct = h * 8 + ctl;
                #pragma unroll
                for (int ks2 = 0; ks2 < 2; ++ks2) {
                    bf16x8 bh = *(const bf16x8*)&xh[(ctl * 16 + m) * STR + ks2 * 32 + quad * 8];
                    bf16x8 bl = *(const bf16x8*)&xl[(ctl * 16 + m) * STR + ks2 * 32 + quad * 8];
                    acc2[ct] = __builtin_amdgcn_mfma_f32_16x16x32_bf16(ah[ks2], bh, acc2[ct], 0, 0, 0);
                    acc2[ct] = __builtin_amdgcn_mfma_f32_16x16x32_bf16(ah[ks2], bl, acc2[ct], 0, 0, 0);
                    acc2[ct] = __builtin_amdgcn_mfma_f32_16x16x32_bf16(al[ks2], bh, acc2[ct], 0, 0, 0);
                }
            }
            __syncthreads();   // readers done before next stage overwrites
        }
    }

    // ---------- store partial 64x256 tile (no atomics) + S ----------
    float* dst = partial + (size_t)(b * split + sp) * 64 * 256;
    #pragma unroll
    for (int ct = 0; ct < 16; ++ct)
        #pragma unroll
        for (int r = 0; r < 4; ++r)
            dst[(w * 16 + quad * 4 + r) * 256 + ct * 16 + m] = acc2[ct][r];

    #pragma unroll
    for (int nt = 0; nt < 4; ++nt) {
        float sv = saccv[nt];
        sv += __shfl_xor(sv, 16);
        sv += __shfl_xor(sv, 32);
        if (quad == 0) atomicAdd(S + b * 64 + nt * 16 + m, sv);
    }
}

// ---------------- Phase 4a: reduce partials, subtract S*centroid, intra-normalize ----------------
__global__ __launch_bounds__(256) void p4a_vlad(
    const float* __restrict__ partial, const float* __restrict__ S,
    const float* __restrict__ cents, float* __restrict__ v, int split)
{
    const int b = blockIdx.x >> 6, k = blockIdx.x & 63;
    const int t = threadIdx.x;
    float sum = 0.f;
    const float* base = partial + ((size_t)(b * split) * 64 + k) * 256 + t;
    for (int sp = 0; sp < split; ++sp)
        sum += base[(size_t)sp * 64 * 256];
    float val = sum - S[b * 64 + k] * cents[k * 256 + t];
    float sq = val * val;
    #pragma unroll
    for (int off = 32; off >= 1; off >>= 1) sq += __shfl_xor(sq, off);
    __shared__ float wsum[4];
    if ((t & 63) == 0) wsum[t >> 6] = sq;
    __syncthreads();
    float tot = wsum[0] + wsum[1] + wsum[2] + wsum[3];
    float r = 1.0f / fmaxf(sqrtf(tot), 1e-12f);
    v[b * 16384 + k * 256 + t] = val * r;
}

// ---------------- Phase 4b: FC out = v @ fc_w.T + fc_b ----------------
__global__ __launch_bounds__(256) void p4b_fc(
    const float* __restrict__ v, const float* __restrict__ fcw,
    const float* __restrict__ fcb, float* __restrict__ pre)
{
    const int t = threadIdx.x;
    const int o0 = blockIdx.x * 4;
    float acc[4][8] = {};
    for (int it = 0; it < 64; ++it) {
        int i = it * 256 + t;
        float wv[4];
        #pragma unroll
        for (int oo = 0; oo < 4; ++oo) wv[oo] = fcw[(size_t)(o0 + oo) * 16384 + i];
        #pragma unroll
        for (int b = 0; b < 8; ++b) {
            float vv = v[b * 16384 + i];
            #pragma unroll
            for (int oo = 0; oo < 4; ++oo) acc[oo][b] += wv[oo] * vv;
        }
    }
    __shared__ float red[32][4];
    #pragma unroll
    for (int oo = 0; oo < 4; ++oo)
        #pragma unroll
        for (int b = 0; b < 8; ++b) {
            float sv = acc[oo][b];
            #pragma unroll
            for (int off = 32; off >= 1; off >>= 1) sv += __shfl_xor(sv, off);
            if ((t & 63) == 0) red[oo * 8 + b][t >> 6] = sv;
        }
    __syncthreads();
    if (t < 32) {
        int oo = t >> 3, b = t & 7;
        float sv = red[t][0] + red[t][1] + red[t][2] + red[t][3];
        pre[b * 1024 + o0 + oo] = sv + fcb[o0 + oo];
    }
}

// ---------------- Phase 5: final l2norm over 1024 ----------------
__global__ __launch_bounds__(256) void p5_norm(const float* __restrict__ pre, float* __restrict__ out)
{
    const int b = blockIdx.x, t = threadIdx.x;
    float vals[4];
    float sq = 0.f;
    #pragma unroll
    for (int i = 0; i < 4; ++i) {
        vals[i] = pre[b * 1024 + t + 256 * i];
        sq += vals[i] * vals[i];
    }
    #pragma unroll
    for (int off = 32; off >= 1; off >>= 1) sq += __shfl_xor(sq, off);
    __shared__ float wsum[4];
    if ((t & 63) == 0) wsum[t >> 6] = sq;
    __syncthreads();
    float tot = wsum[0] + wsum[1] + wsum[2] + wsum[3];
    float r = 1.0f / fmaxf(sqrtf(tot), 1e-12f);
    #pragma unroll
    for (int i = 0; i < 4; ++i) out[b * 1024 + t + 256 * i] = vals[i] * r;
}

extern "C" void kernel_launch(void* const* d_in, const int* in_sizes, int n_in,
                              void* d_out, int out_size, void* d_ws, size_t ws_size,
                              hipStream_t stream)
{
    const float* feat  = (const float*)d_in[0];
    const int*   bids  = (const int*)d_in[1];
    const float* cents = (const float*)d_in[2];
    const float* convw = (const float*)d_in[3];
    const float* convb = (const float*)d_in[4];
    const float* fcw   = (const float*)d_in[5];
    const float* fcb   = (const float*)d_in[6];
    float* out = (float*)d_out;

    const int N = in_sizes[0] / 256;  // 200000

    // ---- adaptive split: 64 => 512 blocks = 2 resident per CU
    const size_t base_floats = 16384 /*whi+wlo float-equiv*/ + 512 /*S*/
                             + 8 * 16384 /*v*/ + 8192 /*pre*/;
    const size_t base_ints = (size_t)N + 8 + 9 + 8;
    int split = 64;
    while (split > 16) {
        size_t tot = (base_floats + (size_t)split * 8 * 16384) * 4 + base_ints * 4;
        if (tot <= ws_size) break;
        split -= 16;
    }

    short* whi = (short*)d_ws;                          // 16384 shorts
    short* wlo = whi + 16384;                           // 16384 shorts
    float* partial = (float*)(wlo + 16384);             // split*8*16384
    float* S    = partial + (size_t)split * 8 * 16384;  // 512
    int* cnts = (int*)(S + 512);                        // 8  (adjacent to S: one memset)
    int* offs = cnts + 8;                               // 9
    int* cur  = offs + 9;                               // 8
    float* v    = (float*)(cur + 8);                    // 8*16384
    float* pre  = v + 8 * 16384;                        // 8192
    int* perm = (int*)(pre + 8192);                     // N

    hipMemsetAsync(S, 0, 512 * sizeof(float) + 8 * sizeof(int), stream);

    p0_wsplit<<<8, 256, 0, stream>>>(convw, whi, wlo);
    p2_count<<<(N + 255) / 256, 256, 0, stream>>>(bids, cnts, N);
    p2_offsets<<<1, 64, 0, stream>>>(cnts, offs, cur);
    p2_scatter<<<(N + 255) / 256, 256, 0, stream>>>(bids, cur, perm, N);
    fused13<<<8 * split, 256, 0, stream>>>(feat, whi, wlo, convb, perm, offs, partial, S, split);
    p4a_vlad<<<512, 256, 0, stream>>>(partial, S, cents, v, split);
    p4b_fc<<<256, 256, 0, stream>>>(v, fcw, fcb, pre);
    p5_norm<<<8, 256, 0, stream>>>(pre, out);
}